// Round 1
// baseline (353.059 us; speedup 1.0000x reference)
//
#include <hip/hip_runtime.h>

// DistMult: out[n1,n2] = (input1 * w[type]) @ input2^T + bias
// n1=n2=8192, d=512, fp32 in/out. Strategy: fp32->bf16 convert (w_r scale fused),
// then m97-style bf16 MFMA NT-GEMM (128x128 tile, BK=32, global_load_lds 16B).

#define N1 8192
#define N2 8192
#define DK 512
#define BM 128
#define BN 128
#define BK 32

typedef short bf16x8 __attribute__((ext_vector_type(8)));
typedef float f32x4 __attribute__((ext_vector_type(4)));

__device__ __forceinline__ unsigned short f2bf(float f) {
    unsigned int u = __float_as_uint(f);
    u = (u + 0x7FFFu + ((u >> 16) & 1u)) >> 16;  // round-to-nearest-even
    return (unsigned short)u;
}

// One pass over both inputs: A-region gets w_r scaling, B-region straight cast.
__global__ __launch_bounds__(256) void convert_kernel(
        const float* __restrict__ in1, const float* __restrict__ in2,
        const float* __restrict__ weight, const int* __restrict__ type_index,
        unsigned short* __restrict__ a_bf, unsigned short* __restrict__ b_bf) {
    const int QA = N1 * DK / 4;
    int i = blockIdx.x * blockDim.x + threadIdx.x;
    if (i < QA) {
        float4 v = reinterpret_cast<const float4*>(in1)[i];
        int c4 = i & (DK / 4 - 1);
        float4 w = reinterpret_cast<const float4*>(weight + (size_t)(*type_index) * DK)[c4];
        ushort4 o;
        o.x = f2bf(v.x * w.x);
        o.y = f2bf(v.y * w.y);
        o.z = f2bf(v.z * w.z);
        o.w = f2bf(v.w * w.w);
        reinterpret_cast<ushort4*>(a_bf)[i] = o;
    } else {
        int j = i - QA;
        float4 v = reinterpret_cast<const float4*>(in2)[j];
        ushort4 o;
        o.x = f2bf(v.x);
        o.y = f2bf(v.y);
        o.z = f2bf(v.z);
        o.w = f2bf(v.w);
        reinterpret_cast<ushort4*>(b_bf)[j] = o;
    }
}

// NT GEMM: C[m][n] = sum_k A[m][k]*B[n][k] + bias. A,B bf16 row-major [*,DK].
// Block 256 thr = 4 waves; 128x128 C-tile; each wave a 64x64 sub-tile via
// 4x4 of mfma_f32_16x16x32_bf16.
__global__ __launch_bounds__(256) void gemm_bt(
        const unsigned short* __restrict__ A, const unsigned short* __restrict__ B,
        const float* __restrict__ bias, float* __restrict__ C) {
    __shared__ __align__(16) unsigned short ldsA[BM * BK];  // 8 KB
    __shared__ __align__(16) unsigned short ldsB[BN * BK];  // 8 KB

    const int tid  = threadIdx.x;
    const int wave = tid >> 6;
    const int lane = tid & 63;
    const int quad = lane >> 4;
    const int r16  = lane & 15;
    const int wm   = wave & 1;   // wave's M half
    const int wn   = wave >> 1;  // wave's N half

    const int bm = blockIdx.y * BM;
    const int bn = blockIdx.x * BN;

    f32x4 acc[4][4];
#pragma unroll
    for (int i = 0; i < 4; ++i)
#pragma unroll
        for (int j = 0; j < 4; ++j)
            acc[i][j] = (f32x4){0.f, 0.f, 0.f, 0.f};

    // global_load_lds staging: chunk c = wave*2+it covers tile rows [c*16,c*16+16),
    // lane -> row c*16 + lane/4, col (lane&3)*8 ; LDS dest = base + lane*16B
    // (lane-contiguous row-major layout, element off = c*512 + lane*8).
    const int srow = wave * 32 + (lane >> 2);
    const int scol = (lane & 3) * 8;
    const unsigned short* ag0 = A + (size_t)(bm + srow) * DK + scol;
    const unsigned short* ag1 = ag0 + 16 * DK;
    const unsigned short* bg0 = B + (size_t)(bn + srow) * DK + scol;
    const unsigned short* bg1 = bg0 + 16 * DK;

    unsigned short* la0 = &ldsA[wave * 1024];
    unsigned short* la1 = &ldsA[wave * 1024 + 512];
    unsigned short* lb0 = &ldsB[wave * 1024];
    unsigned short* lb1 = &ldsB[wave * 1024 + 512];

    for (int kt = 0; kt < DK; kt += BK) {
        __builtin_amdgcn_global_load_lds(ag0 + kt, la0, 16, 0, 0);
        __builtin_amdgcn_global_load_lds(ag1 + kt, la1, 16, 0, 0);
        __builtin_amdgcn_global_load_lds(bg0 + kt, lb0, 16, 0, 0);
        __builtin_amdgcn_global_load_lds(bg1 + kt, lb1, 16, 0, 0);
        __syncthreads();

        // A-operand frag: A[m=lane&15][k=quad*8+j]; B-operand: B[k][n=lane&15]
        // -> both read 8 contiguous bf16 at (row=r16-based, col=quad*8): ds_read_b128
        bf16x8 af[4], bfr[4];
#pragma unroll
        for (int mi = 0; mi < 4; ++mi)
            af[mi] = *(const bf16x8*)&ldsA[(wm * 64 + mi * 16 + r16) * BK + quad * 8];
#pragma unroll
        for (int ni = 0; ni < 4; ++ni)
            bfr[ni] = *(const bf16x8*)&ldsB[(wn * 64 + ni * 16 + r16) * BK + quad * 8];

#pragma unroll
        for (int mi = 0; mi < 4; ++mi)
#pragma unroll
            for (int ni = 0; ni < 4; ++ni)
                acc[mi][ni] = __builtin_amdgcn_mfma_f32_16x16x32_bf16(
                    af[mi], bfr[ni], acc[mi][ni], 0, 0, 0);
        __syncthreads();
    }

    // Epilogue: C/D mapping col=lane&15, row=quad*4+reg (verified m89/m91).
    const float bv = bias[0];
#pragma unroll
    for (int mi = 0; mi < 4; ++mi) {
        const int row0 = bm + wm * 64 + mi * 16 + quad * 4;
#pragma unroll
        for (int ni = 0; ni < 4; ++ni) {
            const int col = bn + wn * 64 + ni * 16 + r16;
#pragma unroll
            for (int r = 0; r < 4; ++r)
                C[(size_t)(row0 + r) * N2 + col] = acc[mi][ni][r] + bv;
        }
    }
}

// Fallback if workspace is too small for the bf16 copies (correct but slow).
__global__ void naive_kernel(const float* __restrict__ in1, const float* __restrict__ in2,
                             const float* __restrict__ weight, const int* __restrict__ type_index,
                             const float* __restrict__ bias, float* __restrict__ out) {
    int col = blockIdx.x * 16 + threadIdx.x;
    int row = blockIdx.y * 16 + threadIdx.y;
    const float* wr = weight + (size_t)(*type_index) * DK;
    float s = 0.f;
    for (int k = 0; k < DK; ++k)
        s += in1[(size_t)row * DK + k] * wr[k] * in2[(size_t)col * DK + k];
    out[(size_t)row * N2 + col] = s + bias[0];
}

extern "C" void kernel_launch(void* const* d_in, const int* in_sizes, int n_in,
                              void* d_out, int out_size, void* d_ws, size_t ws_size,
                              hipStream_t stream) {
    const float* in1  = (const float*)d_in[0];
    const float* in2  = (const float*)d_in[1];
    const float* wgt  = (const float*)d_in[2];
    const float* bias = (const float*)d_in[3];
    const int*   tix  = (const int*)d_in[4];
    float* out = (float*)d_out;

    const size_t need = 2ull * (N1 + N2) * DK;  // bf16 copies of A(scaled)+B = 16 MB
    if (ws_size >= need) {
        unsigned short* a_bf = (unsigned short*)d_ws;
        unsigned short* b_bf = a_bf + (size_t)N1 * DK;

        const int total4 = (N1 + N2) * DK / 4;
        convert_kernel<<<total4 / 256, 256, 0, stream>>>(in1, in2, wgt, tix, a_bf, b_bf);

        dim3 grid(N2 / BN, N1 / BM);
        gemm_bt<<<grid, 256, 0, stream>>>(a_bf, b_bf, bias, out);
    } else {
        dim3 grid(N2 / 16, N1 / 16);
        dim3 blk(16, 16);
        naive_kernel<<<grid, blk, 0, stream>>>(in1, in2, wgt, tix, bias, out);
    }
}